// Round 1
// baseline (1451.063 us; speedup 1.0000x reference)
//
#include <hip/hip_runtime.h>
#include <hip/hip_bf16.h>

// Sizes (fixed by the reference)
#define T_TOKENS 1024
#define HID      2048
#define NEXP     64
#define TOPK     8
#define MLP      768
#define NPAIR    (T_TOKENS * TOPK)   // 8192

typedef __bf16 bf16x8 __attribute__((ext_vector_type(8)));
typedef float  f32x4  __attribute__((ext_vector_type(4)));

#define LDK 40   // LDS row stride in shorts (16B-aligned fragment reads, 2-way-max bank aliasing)

static __device__ __forceinline__ unsigned short f2bf(float f) {
    __hip_bfloat16 h = __float2bfloat16(f);
    unsigned short u;
    __builtin_memcpy(&u, &h, sizeof(u));
    return u;
}

// ---------------------------------------------------------------------------
// Router: logits = hs @ router_w, top-8 per token, softmax over the 8.
// Block = 256 threads = 4 waves; each wave handles one token (64 experts).
// ---------------------------------------------------------------------------
__global__ __launch_bounds__(256) void router_topk_kernel(
    const float* __restrict__ hs, const float* __restrict__ rw,
    int* __restrict__ sel, float* __restrict__ wts)
{
    const int lane = threadIdx.x & 63;
    const int tg   = threadIdx.x >> 6;
    const int t    = blockIdx.x * 4 + tg;

    const float4* x4 = (const float4*)(hs + (size_t)t * HID);
    float acc = 0.f;
    for (int h4 = 0; h4 < HID / 4; ++h4) {
        float4 xv = x4[h4];
        int hb = h4 * 4 * NEXP + lane;
        acc += xv.x * rw[hb] + xv.y * rw[hb + NEXP]
             + xv.z * rw[hb + 2 * NEXP] + xv.w * rw[hb + 3 * NEXP];
    }

    // iterative top-8 via wave-64 butterfly argmax
    float v = acc;
    float tv[TOPK]; int ti[TOPK];
    for (int i = 0; i < TOPK; ++i) {
        float m = v; int mi = lane;
        for (int off = 32; off > 0; off >>= 1) {
            float om  = __shfl_xor(m, off, 64);
            int   omi = __shfl_xor(mi, off, 64);
            if (om > m || (om == m && omi < mi)) { m = om; mi = omi; }
        }
        tv[i] = m; ti[i] = mi;
        if (lane == mi) v = -__builtin_inff();
    }
    if (lane == 0) {
        float mx = tv[0], s = 0.f, e[TOPK];
        for (int i = 0; i < TOPK; ++i) { e[i] = __expf(tv[i] - mx); s += e[i]; }
        float inv = 1.f / s;
        for (int i = 0; i < TOPK; ++i) {
            wts[t * TOPK + i] = e[i] * inv;
            sel[t * TOPK + i] = ti[i];
        }
    }
}

// ---------------------------------------------------------------------------
// Routing bookkeeping
// ---------------------------------------------------------------------------
__global__ void count_kernel(const int* __restrict__ sel, int* __restrict__ counts)
{
    int p = blockIdx.x * 256 + threadIdx.x;
    if (p < NPAIR) atomicAdd(&counts[sel[p]], 1);
}

__global__ void scan_kernel(const int* __restrict__ counts,
                            int* __restrict__ offsets, int* __restrict__ cursor)
{
    if (threadIdx.x == 0) {
        int s = 0;
        for (int e = 0; e < NEXP; ++e) { offsets[e] = s; cursor[e] = s; s += counts[e]; }
        offsets[NEXP] = s;
    }
}

__global__ void scatter_kernel(const int* __restrict__ sel,
                               int* __restrict__ cursor, int* __restrict__ rows)
{
    int p = blockIdx.x * 256 + threadIdx.x;
    if (p < NPAIR) {
        int e = sel[p];
        int pos = atomicAdd(&cursor[e], 1);
        rows[pos] = p;   // pair id; token = p>>3
    }
}

// ---------------------------------------------------------------------------
// gate/up GEMM + SiLU fused.  Block tile: M=192 rows (all of one expert,
// n_e ~ 128) x N=64 cols, K=2048 in steps of 32.  4 waves, each wave owns
// 48 rows x 64 cols = 3x4 grid of 16x16 MFMA tiles, for BOTH gate and up.
// h = silu(gate)*up written as bf16 to hbuf at the sorted row position.
// ---------------------------------------------------------------------------
__global__ __launch_bounds__(256) void gateup_kernel(
    const float* __restrict__ hs, const float* __restrict__ gw,
    const float* __restrict__ uw, const int* __restrict__ offsets,
    const int* __restrict__ rows, unsigned short* __restrict__ hb)
{
    const int e  = blockIdx.y;
    const int n0 = blockIdx.x * 64;
    const int r0 = offsets[e];
    const int nrows = offsets[e + 1] - r0;
    if (nrows <= 0) return;

    __shared__ unsigned short lA[192 * LDK];
    __shared__ unsigned short lG[64 * LDK];
    __shared__ unsigned short lU[64 * LDK];

    const int thr  = threadIdx.x;
    const int wave = thr >> 6;
    const int lane = thr & 63;
    const int fr   = lane & 15;   // fragment row/col within 16
    const int fq   = lane >> 4;   // quad -> k-segment

    const size_t wbase = (size_t)e * HID * MLP + n0;

    for (int m0 = 0; m0 < nrows; m0 += 192) {
        f32x4 accG[3][4], accU[3][4];
        for (int ms = 0; ms < 3; ++ms)
            for (int ns = 0; ns < 4; ++ns) {
                accG[ms][ns] = (f32x4){0.f, 0.f, 0.f, 0.f};
                accU[ms][ns] = (f32x4){0.f, 0.f, 0.f, 0.f};
            }

        for (int k0 = 0; k0 < HID; k0 += 32) {
            // --- stage A: 192 rows x 32 k, gathered from hs, fp32 -> bf16
            for (int idx = thr; idx < 192 * 4; idx += 256) {
                int r = idx >> 2, c = idx & 3;
                int gr = m0 + r;
                unsigned short v[8] = {0, 0, 0, 0, 0, 0, 0, 0};
                if (gr < nrows) {
                    int p = rows[r0 + gr];
                    const float* src = hs + (size_t)(p >> 3) * HID + k0 + c * 8;
                    #pragma unroll
                    for (int j = 0; j < 8; ++j) v[j] = f2bf(src[j]);
                }
                uint4 pk; __builtin_memcpy(&pk, v, 16);
                *(uint4*)(lA + r * LDK + c * 8) = pk;
            }
            // --- stage G,U transposed into [n][k] (fragment reads become b128)
            {
                int n  = thr & 63;
                int kb = (thr >> 6) * 8;
                const float* gsrc = gw + wbase + (size_t)(k0 + kb) * MLP + n;
                const float* usrc = uw + wbase + (size_t)(k0 + kb) * MLP + n;
                unsigned short gv[8], uv[8];
                #pragma unroll
                for (int j = 0; j < 8; ++j) {
                    gv[j] = f2bf(gsrc[(size_t)j * MLP]);
                    uv[j] = f2bf(usrc[(size_t)j * MLP]);
                }
                #pragma unroll
                for (int j = 0; j < 8; ++j) {
                    lG[n * LDK + kb + j] = gv[j];
                    lU[n * LDK + kb + j] = uv[j];
                }
            }
            __syncthreads();

            bf16x8 aF[3], gF[4], uF[4];
            #pragma unroll
            for (int ns = 0; ns < 4; ++ns) {
                gF[ns] = *(const bf16x8*)(lG + (ns * 16 + fr) * LDK + fq * 8);
                uF[ns] = *(const bf16x8*)(lU + (ns * 16 + fr) * LDK + fq * 8);
            }
            #pragma unroll
            for (int ms = 0; ms < 3; ++ms)
                aF[ms] = *(const bf16x8*)(lA + (wave * 48 + ms * 16 + fr) * LDK + fq * 8);

            #pragma unroll
            for (int ms = 0; ms < 3; ++ms) {
                if (wave * 48 + ms * 16 < nrows - m0) {  // skip all-padding subtiles
                    #pragma unroll
                    for (int ns = 0; ns < 4; ++ns) {
                        accG[ms][ns] = __builtin_amdgcn_mfma_f32_16x16x32_bf16(
                            aF[ms], gF[ns], accG[ms][ns], 0, 0, 0);
                        accU[ms][ns] = __builtin_amdgcn_mfma_f32_16x16x32_bf16(
                            aF[ms], uF[ns], accU[ms][ns], 0, 0, 0);
                    }
                }
            }
            __syncthreads();
        }

        // epilogue: h = silu(g)*u -> bf16  (C layout: col=lane&15, row=quad*4+i)
        #pragma unroll
        for (int ms = 0; ms < 3; ++ms) {
            #pragma unroll
            for (int i = 0; i < 4; ++i) {
                int lrow = wave * 48 + ms * 16 + fq * 4 + i;
                int grow = m0 + lrow;
                if (grow < nrows) {
                    unsigned short* drow = hb + (size_t)(r0 + grow) * MLP + n0;
                    #pragma unroll
                    for (int ns = 0; ns < 4; ++ns) {
                        float g = accG[ms][ns][i], u = accU[ms][ns][i];
                        float h = g * u / (1.f + __expf(-g));
                        drow[ns * 16 + fr] = f2bf(h);
                    }
                }
            }
        }
    }
}

// ---------------------------------------------------------------------------
// down GEMM: out[token] += w * (h_sorted @ down[e]).  Same tiling, K=768.
// ---------------------------------------------------------------------------
__global__ __launch_bounds__(256) void down_kernel(
    const unsigned short* __restrict__ hb, const float* __restrict__ dw,
    const int* __restrict__ offsets, const int* __restrict__ rows,
    const float* __restrict__ wts, float* __restrict__ out)
{
    const int e  = blockIdx.y;
    const int n0 = blockIdx.x * 64;
    const int r0 = offsets[e];
    const int nrows = offsets[e + 1] - r0;
    if (nrows <= 0) return;

    __shared__ unsigned short lA[192 * LDK];
    __shared__ unsigned short lW[64 * LDK];

    const int thr  = threadIdx.x;
    const int wave = thr >> 6;
    const int lane = thr & 63;
    const int fr   = lane & 15;
    const int fq   = lane >> 4;

    const size_t wbase = (size_t)e * MLP * HID + n0;

    for (int m0 = 0; m0 < nrows; m0 += 192) {
        f32x4 acc[3][4];
        for (int ms = 0; ms < 3; ++ms)
            for (int ns = 0; ns < 4; ++ns) acc[ms][ns] = (f32x4){0.f, 0.f, 0.f, 0.f};

        for (int k0 = 0; k0 < MLP; k0 += 32) {
            // --- stage A from hbuf (already bf16, already sorted)
            for (int idx = thr; idx < 192 * 4; idx += 256) {
                int r = idx >> 2, c = idx & 3;
                int gr = m0 + r;
                uint4 v = make_uint4(0, 0, 0, 0);
                if (gr < nrows)
                    v = *(const uint4*)(hb + (size_t)(r0 + gr) * MLP + k0 + c * 8);
                *(uint4*)(lA + r * LDK + c * 8) = v;
            }
            // --- stage W transposed
            {
                int n  = thr & 63;
                int kb = (thr >> 6) * 8;
                const float* src = dw + wbase + (size_t)(k0 + kb) * HID + n;
                unsigned short v[8];
                #pragma unroll
                for (int j = 0; j < 8; ++j) v[j] = f2bf(src[(size_t)j * HID]);
                #pragma unroll
                for (int j = 0; j < 8; ++j) lW[n * LDK + kb + j] = v[j];
            }
            __syncthreads();

            bf16x8 aF[3], bF[4];
            #pragma unroll
            for (int ns = 0; ns < 4; ++ns)
                bF[ns] = *(const bf16x8*)(lW + (ns * 16 + fr) * LDK + fq * 8);
            #pragma unroll
            for (int ms = 0; ms < 3; ++ms)
                aF[ms] = *(const bf16x8*)(lA + (wave * 48 + ms * 16 + fr) * LDK + fq * 8);

            #pragma unroll
            for (int ms = 0; ms < 3; ++ms) {
                if (wave * 48 + ms * 16 < nrows - m0) {
                    #pragma unroll
                    for (int ns = 0; ns < 4; ++ns)
                        acc[ms][ns] = __builtin_amdgcn_mfma_f32_16x16x32_bf16(
                            aF[ms], bF[ns], acc[ms][ns], 0, 0, 0);
                }
            }
            __syncthreads();
        }

        // epilogue: scale by routing weight, accumulate into out[token]
        #pragma unroll
        for (int ms = 0; ms < 3; ++ms) {
            #pragma unroll
            for (int i = 0; i < 4; ++i) {
                int lrow = wave * 48 + ms * 16 + fq * 4 + i;
                int grow = m0 + lrow;
                if (grow < nrows) {
                    int p  = rows[r0 + grow];
                    float w = wts[p];
                    float* orow = out + (size_t)(p >> 3) * HID + n0;
                    #pragma unroll
                    for (int ns = 0; ns < 4; ++ns)
                        atomicAdd(orow + ns * 16 + fr, acc[ms][ns][i] * w);
                }
            }
        }
    }
}

// ---------------------------------------------------------------------------
extern "C" void kernel_launch(void* const* d_in, const int* in_sizes, int n_in,
                              void* d_out, int out_size, void* d_ws, size_t ws_size,
                              hipStream_t stream)
{
    const float* hs = (const float*)d_in[0];   // [1024, 2048]
    const float* rw = (const float*)d_in[1];   // [2048, 64]
    const float* gw = (const float*)d_in[2];   // [64, 2048, 768]
    const float* uw = (const float*)d_in[3];   // [64, 2048, 768]
    const float* dw = (const float*)d_in[4];   // [64, 768, 2048]
    float* out = (float*)d_out;                // [1024, 2048]

    char* ws = (char*)d_ws;
    int*   sel     = (int*)(ws);                         // 8192 ints
    float* wts     = (float*)(ws + 32768);               // 8192 floats
    int*   counts  = (int*)(ws + 65536);                 // 64
    int*   offsets = (int*)(ws + 65792);                 // 65
    int*   cursor  = (int*)(ws + 66304);                 // 64
    int*   rows    = (int*)(ws + 66560);                 // 8192
    unsigned short* hb = (unsigned short*)(ws + 99328);  // 8192*768 bf16 = 12.6 MB

    hipMemsetAsync(out, 0, (size_t)T_TOKENS * HID * sizeof(float), stream);
    hipMemsetAsync(counts, 0, NEXP * sizeof(int), stream);

    router_topk_kernel<<<T_TOKENS / 4, 256, 0, stream>>>(hs, rw, sel, wts);
    count_kernel<<<NPAIR / 256, 256, 0, stream>>>(sel, counts);
    scan_kernel<<<1, 64, 0, stream>>>(counts, offsets, cursor);
    scatter_kernel<<<NPAIR / 256, 256, 0, stream>>>(sel, cursor, rows);
    gateup_kernel<<<dim3(MLP / 64, NEXP), 256, 0, stream>>>(hs, gw, uw, offsets, rows, hb);
    down_kernel<<<dim3(HID / 64, NEXP), 256, 0, stream>>>(hb, dw, offsets, rows, wts, out);
}